// Round 8
// baseline (247.255 us; speedup 1.0000x reference)
//
#include <hip/hip_runtime.h>
#include <hip/hip_bf16.h>

// CORAL ordinal-regression loss, mean-reduced.
// loss[i,k] = max(x,0) - x*[t_i > k] + log1p(exp(-|x|)),  x = logits[i,k]
//           = fmax(y,0) + log1p(exp(-|x|)),  y = (t_i > k) ? -x : x
// Log fusion per quad: sum_e log1p(e_e) = ln2 * log2( prod_e (1+e_e) ),
//   e_e = exp2(-log2e*|x_e|) in (0,1] -> each factor in (1,2], prod <= 16.
// out[0] = mean(loss)
//
// Single fused dispatch (threadfence-reduction): every block writes its
// partial to d_ws, device-scope fence, atomicAdd on a counter; the LAST
// block fences (L1 invalidate) and reduces all partials in a FIXED order
// -> bitwise-deterministic. Counter zeroed per call via 4B hipMemsetAsync.
//
// Memory mapping unchanged from R7 (flat coalesced quads, QPT=5 exact,
// nontemporal logits loads): measured ~5.5 TB/s effective, near ceiling.

#define NTHREADS 256
#define QPT 5             // quads per thread (exact path)

typedef float f32x4 __attribute__((ext_vector_type(4)));

__device__ __forceinline__ float hw_exp2(float a) { return __builtin_amdgcn_exp2f(a); }  // v_exp_f32
__device__ __forceinline__ float hw_log2(float a) { return __builtin_amdgcn_logf(a); }   // v_log_f32

__device__ __forceinline__ void coral_quad(const f32x4 v, const int d,
                                           float& acc_relu, float& acc_l2) {
    const float c = -1.44269504088896f;  // -log2(e); abs folds into the mul
    const float e0 = hw_exp2(c * fabsf(v.x));
    const float e1 = hw_exp2(c * fabsf(v.y));
    const float e2 = hw_exp2(c * fabsf(v.z));
    const float e3 = hw_exp2(c * fabsf(v.w));
    acc_l2 += hw_log2(((1.f + e0) * (1.f + e1)) * ((1.f + e2) * (1.f + e3)));
    const float y0 = (d > 0) ? -v.x : v.x;
    const float y1 = (d > 1) ? -v.y : v.y;
    const float y2 = (d > 2) ? -v.z : v.z;
    const float y3 = (d > 3) ? -v.w : v.w;
    acc_relu += (fmaxf(y0, 0.f) + fmaxf(y1, 0.f)) + (fmaxf(y2, 0.f) + fmaxf(y3, 0.f));
}

__device__ __forceinline__ float block_reduce_epilogue(float acc, float* s) {
    #pragma unroll
    for (int off = 32; off > 0; off >>= 1)
        acc += __shfl_down(acc, off, 64);
    const int lane = threadIdx.x & 63;
    const int wave = threadIdx.x >> 6;
    if (lane == 0) s[wave] = acc;
    __syncthreads();
    float b = 0.0f;
    if (threadIdx.x == 0) {
        #pragma unroll
        for (int w = 0; w < NTHREADS / 64; ++w) b += s[w];
    }
    return b;
}

// Fused: partial sums + last-block final reduction (deterministic).
__global__ __launch_bounds__(NTHREADS) void coral_fused(
    const f32x4* __restrict__ logits4,
    const int* __restrict__ targets,
    float* __restrict__ partials,
    unsigned int* __restrict__ counter,   // zeroed via hipMemsetAsync per call
    float* __restrict__ out,
    int stride,                           // = total threads = total_quads / QPT
    int n_blocks,
    float inv_n)
{
    const int tid = blockIdx.x * NTHREADS + threadIdx.x;

    f32x4 x[QPT];
    int   d[QPT];
    #pragma unroll
    for (int k = 0; k < QPT; ++k) {
        const int j   = tid + k * stride;
        const int row = j / 25;               // magic-mul
        const int kb  = (j - row * 25) * 4;
        x[k] = __builtin_nontemporal_load(&logits4[j]);   // global_load_dwordx4 nt
        d[k] = targets[row] - kb;             // element c selected iff d > c
    }

    float acc_relu = 0.0f, acc_l2 = 0.0f;
    #pragma unroll
    for (int k = 0; k < QPT; ++k)
        coral_quad(x[k], d[k], acc_relu, acc_l2);

    float acc = fmaf(0.69314718055995f, acc_l2, acc_relu);

    __shared__ float s[NTHREADS / 64];
    __shared__ bool is_last;
    const float b = block_reduce_epilogue(acc, s);
    if (threadIdx.x == 0) {
        partials[blockIdx.x] = b;
        __threadfence();                      // release: partial visible device-wide
        is_last = (atomicAdd(counter, 1u) == (unsigned)(n_blocks - 1));
    }
    __syncthreads();

    if (is_last) {
        __threadfence();                      // acquire: invalidate stale L1
        float facc = 0.0f;
        for (int i = threadIdx.x; i < n_blocks; i += NTHREADS)
            facc += partials[i];              // fixed order -> deterministic
        __syncthreads();                      // s[] reuse
        const float total = block_reduce_epilogue(facc, s);
        if (threadIdx.x == 0) out[0] = total * inv_n;
    }
}

// Fallback grid-stride path (only used if sizes aren't the expected ones).
__global__ __launch_bounds__(NTHREADS) void coral_partial_gs(
    const f32x4* __restrict__ logits4,
    const int* __restrict__ targets,
    float* __restrict__ partials,
    int total_quads)
{
    float acc_relu = 0.0f, acc_l2 = 0.0f;
    const int stride = gridDim.x * blockDim.x;
    for (int j = blockIdx.x * blockDim.x + threadIdx.x; j < total_quads; j += stride) {
        const int row = j / 25;
        const int kb  = (j - row * 25) * 4;
        coral_quad(logits4[j], targets[row] - kb, acc_relu, acc_l2);
    }
    float acc = fmaf(0.69314718055995f, acc_l2, acc_relu);

    __shared__ float s[NTHREADS / 64];
    const float b = block_reduce_epilogue(acc, s);
    if (threadIdx.x == 0) partials[blockIdx.x] = b;
}

__global__ __launch_bounds__(NTHREADS) void coral_final_kernel(
    const float* __restrict__ partials,
    float* __restrict__ out,
    int n_partials,
    float inv_n)
{
    float acc = 0.0f;
    for (int i = threadIdx.x; i < n_partials; i += NTHREADS)
        acc += partials[i];
    __shared__ float s[NTHREADS / 64];
    const float b = block_reduce_epilogue(acc, s);
    if (threadIdx.x == 0) out[0] = b * inv_n;
}

extern "C" void kernel_launch(void* const* d_in, const int* in_sizes, int n_in,
                              void* d_out, int out_size, void* d_ws, size_t ws_size,
                              hipStream_t stream) {
    const float* logits  = (const float*)d_in[0];
    const int*   targets = (const int*)d_in[1];
    float* out = (float*)d_out;
    float* partials = (float*)d_ws;

    const int n_elems     = in_sizes[0];          // B * KM1 = 26,214,400
    const int total_quads = n_elems / 4;          // 6,553,600
    const float inv_n = 1.0f / (float)n_elems;

    if (total_quads % (QPT * NTHREADS) == 0) {
        const int n_threads_total = total_quads / QPT;      // 1,310,720
        const int n_blocks = n_threads_total / NTHREADS;    // 5120
        // counter placed after partials, 64B-aligned
        unsigned int* counter =
            (unsigned int*)((char*)d_ws + ((size_t)n_blocks * sizeof(float) + 63) / 64 * 64);
        hipMemsetAsync(counter, 0, sizeof(unsigned int), stream);
        coral_fused<<<n_blocks, NTHREADS, 0, stream>>>(
            (const f32x4*)logits, targets, partials, counter, out,
            n_threads_total, n_blocks, inv_n);
    } else {
        const int n_blocks = 2048;
        coral_partial_gs<<<n_blocks, NTHREADS, 0, stream>>>(
            (const f32x4*)logits, targets, partials, total_quads);
        coral_final_kernel<<<1, NTHREADS, 0, stream>>>(
            partials, out, n_blocks, inv_n);
    }
}

// Round 9
// 25.059 us; speedup vs baseline: 9.8670x; 9.8670x over previous
//
#include <hip/hip_runtime.h>
#include <hip/hip_bf16.h>

// CORAL ordinal-regression loss, mean-reduced.
// loss[i,k] = max(x,0) - x*[t_i > k] + log1p(exp(-|x|)),  x = logits[i,k]
//           = fmax(y,0) + log1p(exp(-|x|)),  y = (t_i > k) ? -x : x
// Log fusion per quad: sum_e log1p(e_e) = ln2 * log2( prod_e (1+e_e) ),
//   e_e = exp2(-log2e*|x_e|) in (0,1] -> each factor in (1,2], prod <= 16.
// out[0] = mean(loss)
//
// Structure: TWO dispatches. R8 proved single-dispatch fusion via
// __threadfence is a disaster on CDNA4 (agent-scope fence = L2
// writeback/invalidate per block; 5120 of them cost ~230us). The kernel
// boundary provides the device-wide release/acquire for free.
//
// Kernel 1 (hot): flat coalesced quads, QPT=5 exact (5120 blocks x 256),
// all 10 loads up front, nontemporal logits loads (~5.5 TB/s, 87% of the
// 6.3 TB/s achievable ceiling, VGPR=24 -> max occupancy).
// Kernel 2: one 1024-thread block, vectorized partial loads.

#define NTHREADS 256
#define QPT 5             // quads per thread (exact path)
#define FINAL_THREADS 1024

typedef float f32x4 __attribute__((ext_vector_type(4)));

__device__ __forceinline__ float hw_exp2(float a) { return __builtin_amdgcn_exp2f(a); }  // v_exp_f32
__device__ __forceinline__ float hw_log2(float a) { return __builtin_amdgcn_logf(a); }   // v_log_f32

__device__ __forceinline__ void coral_quad(const f32x4 v, const int d,
                                           float& acc_relu, float& acc_l2) {
    const float c = -1.44269504088896f;  // -log2(e); abs folds into the mul
    const float e0 = hw_exp2(c * fabsf(v.x));
    const float e1 = hw_exp2(c * fabsf(v.y));
    const float e2 = hw_exp2(c * fabsf(v.z));
    const float e3 = hw_exp2(c * fabsf(v.w));
    acc_l2 += hw_log2(((1.f + e0) * (1.f + e1)) * ((1.f + e2) * (1.f + e3)));
    const float y0 = (d > 0) ? -v.x : v.x;
    const float y1 = (d > 1) ? -v.y : v.y;
    const float y2 = (d > 2) ? -v.z : v.z;
    const float y3 = (d > 3) ? -v.w : v.w;
    acc_relu += (fmaxf(y0, 0.f) + fmaxf(y1, 0.f)) + (fmaxf(y2, 0.f) + fmaxf(y3, 0.f));
}

template <int NT>
__device__ __forceinline__ float block_reduce(float acc, float* s) {
    #pragma unroll
    for (int off = 32; off > 0; off >>= 1)
        acc += __shfl_down(acc, off, 64);
    const int lane = threadIdx.x & 63;
    const int wave = threadIdx.x >> 6;
    if (lane == 0) s[wave] = acc;
    __syncthreads();
    float b = 0.0f;
    if (threadIdx.x == 0) {
        #pragma unroll
        for (int w = 0; w < NT / 64; ++w) b += s[w];
    }
    return b;
}

// Exact path: each thread handles quads {tid + k*stride, k=0..QPT-1}.
__global__ __launch_bounds__(NTHREADS) void coral_partial_exact(
    const f32x4* __restrict__ logits4,
    const int* __restrict__ targets,
    float* __restrict__ partials,
    int stride)                       // = total threads = total_quads / QPT
{
    const int tid = blockIdx.x * NTHREADS + threadIdx.x;

    f32x4 x[QPT];
    int   d[QPT];
    #pragma unroll
    for (int k = 0; k < QPT; ++k) {
        const int j   = tid + k * stride;
        const int row = j / 25;               // magic-mul
        const int kb  = (j - row * 25) * 4;
        x[k] = __builtin_nontemporal_load(&logits4[j]);   // global_load_dwordx4 nt
        d[k] = targets[row] - kb;             // element c selected iff d > c
    }

    float acc_relu = 0.0f, acc_l2 = 0.0f;
    #pragma unroll
    for (int k = 0; k < QPT; ++k)
        coral_quad(x[k], d[k], acc_relu, acc_l2);

    float acc = fmaf(0.69314718055995f, acc_l2, acc_relu);

    __shared__ float s[NTHREADS / 64];
    const float b = block_reduce<NTHREADS>(acc, s);
    if (threadIdx.x == 0)
        __builtin_nontemporal_store(b, &partials[blockIdx.x]);  // skip dirty-L2
}

// Fallback grid-stride path (only used if sizes aren't the expected ones).
__global__ __launch_bounds__(NTHREADS) void coral_partial_gs(
    const f32x4* __restrict__ logits4,
    const int* __restrict__ targets,
    float* __restrict__ partials,
    int total_quads)
{
    float acc_relu = 0.0f, acc_l2 = 0.0f;
    const int stride = gridDim.x * blockDim.x;
    for (int j = blockIdx.x * blockDim.x + threadIdx.x; j < total_quads; j += stride) {
        const int row = j / 25;
        const int kb  = (j - row * 25) * 4;
        coral_quad(logits4[j], targets[row] - kb, acc_relu, acc_l2);
    }
    float acc = fmaf(0.69314718055995f, acc_l2, acc_relu);

    __shared__ float s[NTHREADS / 64];
    const float b = block_reduce<NTHREADS>(acc, s);
    if (threadIdx.x == 0) partials[blockIdx.x] = b;
}

// Final: 1024 threads, vector loads over n_quads = n_partials/4.
__global__ __launch_bounds__(FINAL_THREADS) void coral_final_kernel(
    const f32x4* __restrict__ partials4,
    float* __restrict__ out,
    int n_quads,
    float inv_n)
{
    float acc = 0.0f;
    for (int i = threadIdx.x; i < n_quads; i += FINAL_THREADS) {
        const f32x4 p = partials4[i];
        acc += (p.x + p.y) + (p.z + p.w);
    }

    __shared__ float s[FINAL_THREADS / 64];
    const float b = block_reduce<FINAL_THREADS>(acc, s);
    if (threadIdx.x == 0) out[0] = b * inv_n;
}

// Scalar final for the fallback path (n_partials not divisible by 4 safety).
__global__ __launch_bounds__(NTHREADS) void coral_final_scalar(
    const float* __restrict__ partials,
    float* __restrict__ out,
    int n_partials,
    float inv_n)
{
    float acc = 0.0f;
    for (int i = threadIdx.x; i < n_partials; i += NTHREADS)
        acc += partials[i];
    __shared__ float s[NTHREADS / 64];
    const float b = block_reduce<NTHREADS>(acc, s);
    if (threadIdx.x == 0) out[0] = b * inv_n;
}

extern "C" void kernel_launch(void* const* d_in, const int* in_sizes, int n_in,
                              void* d_out, int out_size, void* d_ws, size_t ws_size,
                              hipStream_t stream) {
    const float* logits  = (const float*)d_in[0];
    const int*   targets = (const int*)d_in[1];
    float* out = (float*)d_out;
    float* partials = (float*)d_ws;

    const int n_elems     = in_sizes[0];          // B * KM1 = 26,214,400
    const int total_quads = n_elems / 4;          // 6,553,600
    const float inv_n = 1.0f / (float)n_elems;

    if (total_quads % (QPT * NTHREADS) == 0) {
        const int n_threads_total = total_quads / QPT;      // 1,310,720
        const int n_blocks = n_threads_total / NTHREADS;    // 5120
        coral_partial_exact<<<n_blocks, NTHREADS, 0, stream>>>(
            (const f32x4*)logits, targets, partials, n_threads_total);
        coral_final_kernel<<<1, FINAL_THREADS, 0, stream>>>(
            (const f32x4*)partials, out, n_blocks / 4, inv_n);
    } else {
        const int n_blocks = 2048;
        coral_partial_gs<<<n_blocks, NTHREADS, 0, stream>>>(
            (const f32x4*)logits, targets, partials, total_quads);
        coral_final_scalar<<<1, NTHREADS, 0, stream>>>(
            partials, out, n_blocks, inv_n);
    }
}

// Round 10
// 24.098 us; speedup vs baseline: 10.2603x; 1.0399x over previous
//
#include <hip/hip_runtime.h>
#include <hip/hip_bf16.h>

// CORAL ordinal-regression loss, mean-reduced.
// loss[i,k] = max(x,0) - x*[t_i > k] + log1p(exp(-|x|)),  x = logits[i,k]
//           = fmax(y,0) + log1p(exp(-|x|)),  y = (t_i > k) ? -x : x
// Log fusion per quad: sum_e log1p(e_e) = ln2 * log2( prod_e (1+e_e) ),
//   e_e = exp2(-log2e*|x_e|) in (0,1] -> each factor in (1,2], prod <= 16.
// out[0] = mean(loss)
//
// Best-measured configuration (R7, 23.6 us):
// - TWO dispatches. R8 proved single-dispatch __threadfence fusion costs
//   ~230us on CDNA4 (agent-scope fence per block = L2 writeback).
// - Kernel 1: flat coalesced quads, QPT=5 exact (5120 blocks x 256), all 10
//   loads issued up front, NONTEMPORAL logits loads (~5.5 TB/s effective,
//   87% of the 6.29 TB/s copy ceiling). Plain store for partials (R9 showed
//   NT partial-store / 1024-thread final regress the epilogue by ~1.4us).
// - Kernel 2: one 256-thread block, float4 partial loads.

#define NTHREADS 256
#define QPT 5             // quads per thread (exact path)

typedef float f32x4 __attribute__((ext_vector_type(4)));

__device__ __forceinline__ float hw_exp2(float a) { return __builtin_amdgcn_exp2f(a); }  // v_exp_f32
__device__ __forceinline__ float hw_log2(float a) { return __builtin_amdgcn_logf(a); }   // v_log_f32

__device__ __forceinline__ void coral_quad(const f32x4 v, const int d,
                                           float& acc_relu, float& acc_l2) {
    const float c = -1.44269504088896f;  // -log2(e); abs folds into the mul
    const float e0 = hw_exp2(c * fabsf(v.x));
    const float e1 = hw_exp2(c * fabsf(v.y));
    const float e2 = hw_exp2(c * fabsf(v.z));
    const float e3 = hw_exp2(c * fabsf(v.w));
    acc_l2 += hw_log2(((1.f + e0) * (1.f + e1)) * ((1.f + e2) * (1.f + e3)));
    const float y0 = (d > 0) ? -v.x : v.x;
    const float y1 = (d > 1) ? -v.y : v.y;
    const float y2 = (d > 2) ? -v.z : v.z;
    const float y3 = (d > 3) ? -v.w : v.w;
    acc_relu += (fmaxf(y0, 0.f) + fmaxf(y1, 0.f)) + (fmaxf(y2, 0.f) + fmaxf(y3, 0.f));
}

__device__ __forceinline__ float block_reduce_epilogue(float acc, float* s) {
    #pragma unroll
    for (int off = 32; off > 0; off >>= 1)
        acc += __shfl_down(acc, off, 64);
    const int lane = threadIdx.x & 63;
    const int wave = threadIdx.x >> 6;
    if (lane == 0) s[wave] = acc;
    __syncthreads();
    float b = 0.0f;
    if (threadIdx.x == 0) {
        #pragma unroll
        for (int w = 0; w < NTHREADS / 64; ++w) b += s[w];
    }
    return b;
}

// Exact path: each thread handles quads {tid + k*stride, k=0..QPT-1}.
__global__ __launch_bounds__(NTHREADS) void coral_partial_exact(
    const f32x4* __restrict__ logits4,
    const int* __restrict__ targets,
    float* __restrict__ partials,
    int stride)                       // = total threads = total_quads / QPT
{
    const int tid = blockIdx.x * NTHREADS + threadIdx.x;

    f32x4 x[QPT];
    int   d[QPT];
    #pragma unroll
    for (int k = 0; k < QPT; ++k) {
        const int j   = tid + k * stride;
        const int row = j / 25;               // magic-mul
        const int kb  = (j - row * 25) * 4;
        x[k] = __builtin_nontemporal_load(&logits4[j]);   // global_load_dwordx4 nt
        d[k] = targets[row] - kb;             // element c selected iff d > c
    }

    float acc_relu = 0.0f, acc_l2 = 0.0f;
    #pragma unroll
    for (int k = 0; k < QPT; ++k)
        coral_quad(x[k], d[k], acc_relu, acc_l2);

    float acc = fmaf(0.69314718055995f, acc_l2, acc_relu);

    __shared__ float s[NTHREADS / 64];
    const float b = block_reduce_epilogue(acc, s);
    if (threadIdx.x == 0) partials[blockIdx.x] = b;
}

// Fallback grid-stride path (only used if sizes aren't the expected ones).
__global__ __launch_bounds__(NTHREADS) void coral_partial_gs(
    const f32x4* __restrict__ logits4,
    const int* __restrict__ targets,
    float* __restrict__ partials,
    int total_quads)
{
    float acc_relu = 0.0f, acc_l2 = 0.0f;
    const int stride = gridDim.x * blockDim.x;
    for (int j = blockIdx.x * blockDim.x + threadIdx.x; j < total_quads; j += stride) {
        const int row = j / 25;
        const int kb  = (j - row * 25) * 4;
        coral_quad(logits4[j], targets[row] - kb, acc_relu, acc_l2);
    }
    float acc = fmaf(0.69314718055995f, acc_l2, acc_relu);

    __shared__ float s[NTHREADS / 64];
    const float b = block_reduce_epilogue(acc, s);
    if (threadIdx.x == 0) partials[blockIdx.x] = b;
}

// Final: n_partials is a multiple of 4 -> vector loads, 256 threads.
__global__ __launch_bounds__(NTHREADS) void coral_final_kernel(
    const f32x4* __restrict__ partials4,
    float* __restrict__ out,
    int n_quads,                       // n_partials / 4
    float inv_n)
{
    float acc = 0.0f;
    for (int i = threadIdx.x; i < n_quads; i += NTHREADS) {
        const f32x4 p = partials4[i];
        acc += (p.x + p.y) + (p.z + p.w);
    }

    __shared__ float s[NTHREADS / 64];
    const float b = block_reduce_epilogue(acc, s);
    if (threadIdx.x == 0) out[0] = b * inv_n;
}

// Scalar final for the fallback path.
__global__ __launch_bounds__(NTHREADS) void coral_final_scalar(
    const float* __restrict__ partials,
    float* __restrict__ out,
    int n_partials,
    float inv_n)
{
    float acc = 0.0f;
    for (int i = threadIdx.x; i < n_partials; i += NTHREADS)
        acc += partials[i];
    __shared__ float s[NTHREADS / 64];
    const float b = block_reduce_epilogue(acc, s);
    if (threadIdx.x == 0) out[0] = b * inv_n;
}

extern "C" void kernel_launch(void* const* d_in, const int* in_sizes, int n_in,
                              void* d_out, int out_size, void* d_ws, size_t ws_size,
                              hipStream_t stream) {
    const float* logits  = (const float*)d_in[0];
    const int*   targets = (const int*)d_in[1];
    float* out = (float*)d_out;
    float* partials = (float*)d_ws;

    const int n_elems     = in_sizes[0];          // B * KM1 = 26,214,400
    const int total_quads = n_elems / 4;          // 6,553,600
    const float inv_n = 1.0f / (float)n_elems;

    if (total_quads % (QPT * NTHREADS) == 0) {
        const int n_threads_total = total_quads / QPT;      // 1,310,720
        const int n_blocks = n_threads_total / NTHREADS;    // 5120
        coral_partial_exact<<<n_blocks, NTHREADS, 0, stream>>>(
            (const f32x4*)logits, targets, partials, n_threads_total);
        coral_final_kernel<<<1, NTHREADS, 0, stream>>>(
            (const f32x4*)partials, out, n_blocks / 4, inv_n);
    } else {
        const int n_blocks = 2048;
        coral_partial_gs<<<n_blocks, NTHREADS, 0, stream>>>(
            (const f32x4*)logits, targets, partials, total_quads);
        coral_final_scalar<<<1, NTHREADS, 0, stream>>>(
            partials, out, n_blocks, inv_n);
    }
}